// Round 6
// baseline (5715.629 us; speedup 1.0000x reference)
//
#include <hip/hip_runtime.h>

// LSTM T=1024 B=16 I=H=1024 L=2. f32 in/out, bf16 MFMA internally.
// Round 11: layer-1 split across 128 blocks (grid 192) so per-wave weights
// drop to 16 frags = 64 VGPR (the footprint proven resident in layer-0).
//  - r10 post-mortem: VGPR=104 < 128 proves the RA spilled the pinned 32-frag
//    weight array and re-streams ~256KB/block/step from L2 (~1.9us of the
//    4.38us step). Structural fix instead of fighting the allocator.
//  - Each L1 block owns 8 h-cols; B-frags pack 2 gates x 8 cols per MFMA
//    (per-lane row remap at load time reuses the existing packed layout).
//  - Reduce by waves 0-1 (gate-pair p=w); elementwise by tid<128.
//  - flags1 -> [4][128] tag ring (poll lane checks 2 flags). Ring safety
//    unchanged (cross-block publish spread <= 1 step).

#define T_STEPS 1024
#define TQ 16        // t-chunks for gx gemm grid

typedef unsigned short u16;
typedef unsigned long long u64;
typedef __attribute__((ext_vector_type(8))) __bf16 bf16x8;      // 8 bf16 = 4 VGPR
typedef __attribute__((ext_vector_type(4))) float float4v;      // MFMA C/D + f32 loads
typedef __attribute__((ext_vector_type(4))) unsigned short ushort4v;
typedef __attribute__((ext_vector_type(8))) unsigned short ushort8;

__device__ __forceinline__ float bf2f(u16 h) {
    unsigned u = ((unsigned)h) << 16;
    return __builtin_bit_cast(float, u);
}
__device__ __forceinline__ u16 f2bf(float f) {
    unsigned u = __builtin_bit_cast(unsigned, f);
    u += 0x7fff + ((u >> 16) & 1);   // RNE
    return (u16)(u >> 16);
}

__device__ __forceinline__ float4v mfma16(bf16x8 a, bf16x8 b, float4v c) {
    return __builtin_amdgcn_mfma_f32_16x16x32_bf16(a, b, c, 0, 0, 0);
}
__device__ __forceinline__ unsigned aload(const unsigned* p) {
    return __hip_atomic_load(p, __ATOMIC_RELAXED, __HIP_MEMORY_SCOPE_AGENT);
}
__device__ __forceinline__ void astore(unsigned* p, unsigned v) {
    __hip_atomic_store(p, v, __ATOMIC_RELAXED, __HIP_MEMORY_SCOPE_AGENT);
}
// opaque pin: value can no longer be rematerialized from its defining load
__device__ __forceinline__ void pin(bf16x8& v) {
    asm volatile("" : "+v"(v));
}
// cached 16B global->LDS (for producer-dispatch-ordered data: xpack in gx_gemm)
__device__ __forceinline__ void gld_lds16c(const void* g, void* l) {
    __builtin_amdgcn_global_load_lds(
        (const __attribute__((address_space(1))) unsigned*)g,
        (__attribute__((address_space(3))) unsigned*)l, 16, 0, 0);
}
// LLC-coherent 16B global->LDS (sc0|sc1 = 17): bypasses non-coherent L1/L2.
__device__ __forceinline__ void gld_lds16b(const void* g, void* l) {
    __builtin_amdgcn_global_load_lds(
        (const __attribute__((address_space(1))) unsigned*)g,
        (__attribute__((address_space(3))) unsigned*)l, 16, 0, 17);
}

// ---------------------------------------------------------------- init
__global__ void init_zero(unsigned* __restrict__ flags0,  // 1025*64
                          unsigned* __restrict__ flags1,  // 4*128 ring
                          unsigned* __restrict__ h0,      // 8192 (hist0 slot 0)
                          unsigned* __restrict__ h1) {    // 8192 (hist1 slot 0)
    int i = blockIdx.x * 256 + threadIdx.x;
    const int N0 = 65600, N1 = 512, N2 = 8192, N3 = 8192;
    for (int k = i; k < N0 + N1 + N2 + N3; k += 64 * 256) {
        if (k < N0) flags0[k] = 0u;
        else if (k < N0 + N1) flags1[k - N0] = 0u;
        else if (k < N0 + N1 + N2) h0[k - N0 - N1] = 0u;
        else h1[k - N0 - N1 - N2] = 0u;
    }
}

// ---------------------------------------------------------------- pack
// f32 -> bf16 A/B-frag tiles. dst[tile][kc][lane][8] =
//   src[rowbase+lane%16][kc*32+(lane/16)*8+j]
__device__ __forceinline__ void pack_one(const float* src, u16* dst, int tile, int rowbase) {
    int tid = threadIdx.x;
    ushort8* d = (ushort8*)dst;
#pragma unroll
    for (int it = 0; it < 8; ++it) {
        int c = tid + it * 256;
        int kc = c >> 6, lane = c & 63;
        const float4v* s4 = (const float4v*)(src + (((long)(rowbase + (lane & 15))) << 10)
                                                 + (kc << 5) + ((lane >> 4) << 3));
        float4v lo = s4[0], hi = s4[1];
        ushort8 o;
        o[0] = f2bf(lo[0]); o[1] = f2bf(lo[1]); o[2] = f2bf(lo[2]); o[3] = f2bf(lo[3]);
        o[4] = f2bf(hi[0]); o[5] = f2bf(hi[1]); o[6] = f2bf(hi[2]); o[7] = f2bf(hi[3]);
        d[tile * 2048 + c] = o;
    }
}

__global__ void pack_x(const float* __restrict__ src, u16* __restrict__ dst) {
    pack_one(src, dst, blockIdx.x, blockIdx.x << 4);   // rowbase = t*16
}

// 4 weight matrices in one dispatch: grid 1024, which = blockIdx>>8
__global__ void pack_w(const float* __restrict__ w0, const float* __restrict__ w1,
                       const float* __restrict__ w2, const float* __restrict__ w3,
                       u16* __restrict__ d0, u16* __restrict__ d1,
                       u16* __restrict__ d2, u16* __restrict__ d3) {
    int which = blockIdx.x >> 8, tile = blockIdx.x & 255;
    const float* s = (which == 0) ? w0 : (which == 1) ? w1 : (which == 2) ? w2 : w3;
    u16* d = (which == 0) ? d0 : (which == 1) ? d1 : (which == 2) ? d2 : d3;
    int rowbase = ((tile & 3) << 10) + ((tile >> 2) << 4);
    pack_one(s, d, tile, rowbase);
}

// ---------------------------------------------------------------- gx gemm (layer 0)
// K-split: wave w computes K-slice [256w,256w+256) for all 4 gates, reading only
// its own staged LDS quarter; reduce phase (wave w = gate w) sums partials.
__global__ __launch_bounds__(256, 1) void gx_gemm(
        const u16* __restrict__ xp, const bf16x8* __restrict__ wp,
        const float* __restrict__ bih, const float* __restrict__ bhh,
        u16* __restrict__ gx) {
    __shared__ u64 abuf[4096];              // 32 KB
    __shared__ float4v part[4][4][64];      // 16 KB  [kslice][gate][lane]
    int blk = blockIdx.x, tq = blockIdx.y;
    int tid = threadIdx.x, w = tid >> 6, L = tid & 63;
    int gc = (w << 10) + (blk << 4) + (L & 15);
    float bsum = bih[gc] + bhh[gc];

    bf16x8 wf[32];   // [gate][k] for this wave's K-slice
#pragma unroll
    for (int g = 0; g < 4; ++g) {
        const bf16x8* wpt = wp + (blk * 4 + g) * 2048 + (w * 8) * 64 + L;
#pragma unroll
        for (int k = 0; k < 8; ++k) wf[g * 8 + k] = wpt[k * 64];
    }
#pragma unroll
    for (int i = 0; i < 32; ++i) pin(wf[i]);
    const bf16x8* hp = (const bf16x8*)abuf;

    const int tch = T_STEPS / TQ;
    for (int tt = 0; tt < tch; ++tt) {
        int t = tq * tch + tt;
        const char* src = (const char*)xp + ((size_t)t << 15) + (w << 13) + (L << 4);
        char* dst = (char*)abuf + (w << 13);
#pragma unroll
        for (int i = 0; i < 8; ++i) gld_lds16c(src + i * 1024, dst + i * 1024);
        __builtin_amdgcn_s_waitcnt(0);          // own stage done (own quarter only)
        __builtin_amdgcn_sched_barrier(0);

        float4v acc[4];
#pragma unroll
        for (int g = 0; g < 4; ++g) acc[g] = float4v{0.f, 0.f, 0.f, 0.f};
#pragma unroll
        for (int k = 0; k < 8; ++k) {
            bf16x8 a = hp[(8 * w + k) * 64 + L];
#pragma unroll
            for (int g = 0; g < 4; ++g) acc[g] = mfma16(a, wf[g * 8 + k], acc[g]);
        }
#pragma unroll
        for (int g = 0; g < 4; ++g) part[w][g][L] = acc[g];
        __syncthreads();
        float4v s = part[0][w][L] + part[1][w][L] + part[2][w][L] + part[3][w][L];
        ushort4v o;
#pragma unroll
        for (int r = 0; r < 4; ++r) o[r] = f2bf(s[r] + bsum);
        ((ushort4v*)gx)[((t * 64 + blk) * 4 + w) * 64 + L] = o;
        __syncthreads();    // part reusable next iteration
    }
}

// ---------------------------------------------------------------- fused pipelined scan
// 512 threads, 8 waves. Blocks 0..63: layer 0 (16 h-cols each).
// Blocks 64..191: layer 1, 8 h-cols each, concat-K 2048 over 8 waves,
// B-frags pack (gate 2p | gate 2p+1) x 8 cols -> 16 weight frags/wave.
__global__ __launch_bounds__(512, 1) void lstm_scan2(
        const u16* __restrict__ gx0,     // layer-0 gates_x (C-frag, both biases)
        const bf16x8* __restrict__ wpHh0,
        const bf16x8* __restrict__ wpIh1, const bf16x8* __restrict__ wpHh1,
        const float* __restrict__ bih1, const float* __restrict__ bhh1,
        unsigned* hist0w,                // 1025 slots x 8192 u32 (A-frag h0)
        unsigned* hist1x,                // 1024 slots (slots 1..1024, = dead xpack)
        unsigned* h1s0,                  // slot 0 of hist1 (zeroed)
        unsigned* flags0,                // [1025][64] 0/1
        unsigned* flags1,                // [4][128] ring, tag = step
        float* outbase) {                // d_out
    __shared__ u64 hbuf[8192];              // 64 KB
    __shared__ float4v lds_part[8][4][64];  // 32 KB [kslice][pair/gate][lane]
    __shared__ float4v lds_g[4][64];        // 4 KB

    int tid = threadIdx.x, w = tid >> 6, L = tid & 63;
    int layer = (blockIdx.x >= 64);
    float c = 0.f;
    const bf16x8* hp = (const bf16x8*)hbuf;

    if (!layer) {
        // ---------------- layer 0: K=1024, wave w owns kc [4w,4w+4) ----------------
        int blk = blockIdx.x;
        int m = tid >> 4, j = tid & 15;
        int Lc = ((m >> 2) << 4) | j, rr = m & 3;
        int hcol = (blk << 4) + j;
        int kcw = hcol >> 5, laneg = (hcol >> 3) & 3, jj = hcol & 7;
        int hwoff32 = ((kcw * 64 + m + (laneg << 4)) << 2) + (jj >> 1);
        float* fH = outbase + 16777216;
        float* fC = outbase + 16777216 + 32768;

        bf16x8 wf[16];   // [gate][k], 64 VGPR — resident
#pragma unroll
        for (int g = 0; g < 4; ++g) {
            const bf16x8* wsrc = wpHh0 + (blk * 4 + g) * 2048 + (4 * w) * 64 + L;
#pragma unroll
            for (int k = 0; k < 4; ++k) wf[g * 4 + k] = wsrc[k * 64];
        }
#pragma unroll
        for (int i = 0; i < 16; ++i) pin(wf[i]);

        for (int t = 0; t < T_STEPS; ++t) {
            ushort4v gxv = {0, 0, 0, 0};
            if (w < 4) gxv = ((const ushort4v*)gx0)[((t * 64 + blk) * 4 + w) * 64 + L];
            if (t > 0) {   // every wave polls all 64 flags (lane L <-> flag L)
                unsigned v;
                do { v = aload(&flags0[t * 64 + L]); }
                while (__ballot(v != 0u) != ~0ull);
            }
            {   // stage own 4KB slice of h0(t) -> LDS
                const char* src = (const char*)hist0w + ((size_t)t << 15) + (w << 12) + (L << 4);
                char* dst = (char*)hbuf + (w << 12);
#pragma unroll
                for (int i = 0; i < 4; ++i) gld_lds16b(src + i * 1024, dst + i * 1024);
            }
            __builtin_amdgcn_s_waitcnt(0);
            __builtin_amdgcn_sched_barrier(0);

            float4v acc[4];
#pragma unroll
            for (int g = 0; g < 4; ++g) acc[g] = float4v{0.f, 0.f, 0.f, 0.f};
#pragma unroll
            for (int k = 0; k < 4; ++k) {
                bf16x8 a = hp[(4 * w + k) * 64 + L];
#pragma unroll
                for (int g = 0; g < 4; ++g) acc[g] = mfma16(a, wf[g * 4 + k], acc[g]);
            }
#pragma unroll
            for (int g = 0; g < 4; ++g) lds_part[w][g][L] = acc[g];
            __syncthreads();

            if (w < 4) {   // reduce: wave w = gate w
                float4v s = lds_part[0][w][L] + lds_part[1][w][L]
                          + lds_part[2][w][L] + lds_part[3][w][L]
                          + lds_part[4][w][L] + lds_part[5][w][L]
                          + lds_part[6][w][L] + lds_part[7][w][L];
                float4v g4;
#pragma unroll
                for (int r = 0; r < 4; ++r) g4[r] = s[r] + bf2f(gxv[r]);
                lds_g[w][L] = g4;
            }
            __syncthreads();

            if (tid < 256) {
                float gi = lds_g[0][Lc][rr], gf = lds_g[1][Lc][rr];
                float gg = lds_g[2][Lc][rr], go = lds_g[3][Lc][rr];
                float iv = 1.f / (1.f + __expf(-gi));
                float fv = 1.f / (1.f + __expf(-gf));
                float gv = 1.f - 2.f / (1.f + __expf(2.f * gg));
                float ov = 1.f / (1.f + __expf(-go));
                c = fv * c + iv * gv;
                float h = ov * (1.f - 2.f / (1.f + __expf(2.f * c)));
                unsigned hb = f2bf(h);
                unsigned other = (unsigned)__shfl_xor((int)hb, 1);
                if (!(tid & 1))
                    astore(hist0w + ((size_t)(t + 1) << 13) + hwoff32, hb | (other << 16));
                if (t == T_STEPS - 1) {
                    fH[(m << 10) + hcol] = h;
                    fC[(m << 10) + hcol] = c;
                }
            }
            __builtin_amdgcn_s_waitcnt(0);
            __syncthreads();
            if (tid == 0) astore(&flags0[(t + 1) * 64 + blk], 1u);
        }
    } else {
        // ---------------- layer 1: 128 blocks x 8 h-cols, concat K=2048 ----------
        int blk1 = blockIdx.x - 64;
        int col8 = L & 7, hi8 = (L >> 3) & 1;
        // per-lane source lane in the packed 16-row weight tiles
        int srcl = (L & 48) | (((blk1 & 1) << 3) + col8);
        int kcb = (w < 4) ? (8 * w) : (8 * (w - 4));
        const bf16x8* wbase = (w < 4) ? wpIh1 : wpHh1;

        bf16x8 wf[16];   // [pair][k], 64 VGPR — resident
#pragma unroll
        for (int p = 0; p < 2; ++p) {
            int g = 2 * p + hi8;
            const bf16x8* wsrc = wbase + ((size_t)((blk1 >> 1) * 4 + g)) * 2048
                                       + kcb * 64 + srcl;
#pragma unroll
            for (int k = 0; k < 8; ++k) wf[p * 8 + k] = wsrc[k * 64];
        }
#pragma unroll
        for (int i = 0; i < 16; ++i) pin(wf[i]);

        // bias for reduce lanes (wave w<2 handles pair p=w): col = L&15
        float bsum = 0.f;
        if (w < 2) {
            int g = 2 * w + hi8;
            int grow = (g << 10) + (blk1 << 3) + col8;
            bsum = bih1[grow] + bhh1[grow];
        }

        // elementwise role (tid<128): m = tid>>3 batch, j = tid&7 col
        int m = tid >> 3, j = tid & 7;
        int hcol = (blk1 << 3) + j;
        int kcw = hcol >> 5, laneg = (hcol >> 3) & 3, jj = hcol & 7;
        int hwoff32 = ((kcw * 64 + m + (laneg << 4)) << 2) + (jj >> 1);
        float* fH = outbase + 16777216 + 16384;
        float* fC = outbase + 16777216 + 32768 + 16384;

        for (int t = 0; t < T_STEPS; ++t) {
            if (w < 4) {   // A-half waves need out0(t) = hist0 slot t+1
                unsigned v;
                do { v = aload(&flags0[(t + 1) * 64 + L]); }
                while (__ballot(v != 0u) != ~0ull);
            } else if (t > 0) {   // B-half waves need h1(t): 128 flags, 2 per lane
                unsigned va, vb;
                do {
                    va = aload(&flags1[((t & 3) << 7) + L]);
                    vb = aload(&flags1[((t & 3) << 7) + 64 + L]);
                } while (__ballot(va == (unsigned)t && vb == (unsigned)t) != ~0ull);
            }
            {   // stage own 8KB slice -> LDS
                const char* src = (w < 4)
                    ? ((const char*)hist0w + ((size_t)(t + 1) << 15) + (w << 13) + (L << 4))
                    : ((t == 0)
                        ? ((const char*)h1s0 + ((w - 4) << 13) + (L << 4))
                        : ((const char*)hist1x + ((size_t)(t - 1) << 15) + ((w - 4) << 13) + (L << 4)));
                char* dst = (char*)hbuf + (w << 13);
#pragma unroll
                for (int i = 0; i < 8; ++i) gld_lds16b(src + i * 1024, dst + i * 1024);
            }
            __builtin_amdgcn_s_waitcnt(0);
            __builtin_amdgcn_sched_barrier(0);

            float4v acc0 = {0.f, 0.f, 0.f, 0.f}, acc1 = {0.f, 0.f, 0.f, 0.f};
#pragma unroll
            for (int k = 0; k < 8; ++k) {
                bf16x8 a = hp[(8 * w + k) * 64 + L];
                acc0 = mfma16(a, wf[k], acc0);
                acc1 = mfma16(a, wf[8 + k], acc1);
            }
            lds_part[w][0][L] = acc0;
            lds_part[w][1][L] = acc1;
            __syncthreads();

            if (w < 2) {   // reduce: wave w = pair w (gates 2w, 2w+1)
                float4v s = lds_part[0][w][L] + lds_part[1][w][L]
                          + lds_part[2][w][L] + lds_part[3][w][L]
                          + lds_part[4][w][L] + lds_part[5][w][L]
                          + lds_part[6][w][L] + lds_part[7][w][L];
                float4v g4;
#pragma unroll
                for (int r = 0; r < 4; ++r) g4[r] = s[r] + bsum;
                lds_g[w][L] = g4;
            }
            __syncthreads();

            float h = 0.f;
            if (tid < 128) {
                int base = ((m >> 2) << 4), r = m & 3;
                float gi = lds_g[0][base | j][r];
                float gf = lds_g[0][base | (8 + j)][r];
                float gg = lds_g[1][base | j][r];
                float go = lds_g[1][base | (8 + j)][r];
                float iv = 1.f / (1.f + __expf(-gi));
                float fv = 1.f / (1.f + __expf(-gf));
                float gv = 1.f - 2.f / (1.f + __expf(2.f * gg));
                float ov = 1.f / (1.f + __expf(-go));
                c = fv * c + iv * gv;
                h = ov * (1.f - 2.f / (1.f + __expf(2.f * c)));
                unsigned hb = f2bf(h);
                unsigned other = (unsigned)__shfl_xor((int)hb, 1);
                if (!(tid & 1))   // slot t+1 lives at hist1x + t*32KB
                    astore(hist1x + ((size_t)t << 13) + hwoff32, hb | (other << 16));
            }
            __builtin_amdgcn_s_waitcnt(0);
            __syncthreads();
            if (tid == 0) astore(&flags1[(((t + 1) & 3) << 7) + blk1], (unsigned)(t + 1));
            // not ring-consumed: store after the flag, drains under next poll
            if (tid < 128) {
                outbase[(t << 14) + (m << 10) + hcol] = h;
                if (t == T_STEPS - 1) {
                    fH[(m << 10) + hcol] = h;
                    fC[(m << 10) + hcol] = c;
                }
            }
        }
    }
}

// ---------------------------------------------------------------- launch
extern "C" void kernel_launch(void* const* d_in, const int* in_sizes, int n_in,
                              void* d_out, int out_size, void* d_ws, size_t ws_size,
                              hipStream_t stream) {
    const float* x    = (const float*)d_in[0];
    const float* Wih0 = (const float*)d_in[1];
    const float* bih0 = (const float*)d_in[2];
    const float* Whh0 = (const float*)d_in[3];
    const float* bhh0 = (const float*)d_in[4];
    const float* Wih1 = (const float*)d_in[5];
    const float* bih1 = (const float*)d_in[6];
    const float* Whh1 = (const float*)d_in[7];
    const float* bhh1 = (const float*)d_in[8];
    float* out = (float*)d_out;

    char* ws = (char*)d_ws;
    u16* wpIh0 = (u16*)(ws + 0);            //  8,388,608
    u16* wpHh0 = (u16*)(ws + 8388608);      //  8,388,608
    u16* wpIh1 = (u16*)(ws + 16777216);     //  8,388,608
    u16* wpHh1 = (u16*)(ws + 25165824);     //  8,388,608
    u16* xpack = (u16*)(ws + 33554432);     // 33,554,432 (reused as hist1 slots 1..1024)
    u16* hist0 = (u16*)(ws + 67108864);     // 33,587,200 (1025 x 32KB)
    u16* h1s0  = (u16*)(ws + 100696064);    //     32,768 (hist1 slot 0)
    u16* gxbuf = (u16*)(ws + 100728832);    // 134,217,728
    unsigned* flags0 = (unsigned*)(ws + 234946560); // 262,400
    unsigned* flags1 = (unsigned*)(ws + 235208960); //   2,048 -> 235,211,008 total

    init_zero<<<dim3(64), dim3(256), 0, stream>>>(flags0, flags1,
                                                  (unsigned*)hist0, (unsigned*)h1s0);
    pack_w<<<dim3(1024), dim3(256), 0, stream>>>(Wih0, Whh0, Wih1, Whh1,
                                                 wpIh0, wpHh0, wpIh1, wpHh1);
    pack_x<<<dim3(1024), dim3(256), 0, stream>>>(x, xpack);
    gx_gemm<<<dim3(64, TQ), dim3(256), 0, stream>>>(
        xpack, (const bf16x8*)wpIh0, bih0, bhh0, gxbuf);
    lstm_scan2<<<dim3(192), dim3(512), 0, stream>>>(
        gxbuf, (const bf16x8*)wpHh0, (const bf16x8*)wpIh1, (const bf16x8*)wpHh1,
        bih1, bhh1, (unsigned*)hist0, (unsigned*)xpack, (unsigned*)h1s0,
        flags0, flags1, out);
}

// Round 7
// 4965.737 us; speedup vs baseline: 1.1510x; 1.1510x over previous
//
#include <hip/hip_runtime.h>

// LSTM T=1024 B=16 I=H=1024 L=2. f32 in/out, bf16 MFMA internally.
// Round 12: 16 waves/block (1024 thr), 64+64 blocks — weight-resident WITHOUT
// doubling the ring.
//  - r11 diagnosis: 16-frag/wave weight sets ARE kept resident (VGPR 88), but
//    128-block L1 doubled staging (4->8MB/step) + flag fan-in on the serial
//    chain -> net regression. r10's 8-wave blocks force 32 frags/wave (spilled,
//    re-streamed ~32KB/wave/step from L2 serially inside the MFMA phase).
//  - Fix: frags/wave = 256/waves. 16 waves -> L1 16 frags (64 VGPR, proven
//    resident footprint), L0 8 frags. Same 64-block rings, same flags/publish.
//  - LDS 132KB: hbuf 64K + partials[16][4][64] 64K + lds_g 4K. 1 block/CU.
//  - Stage 16-way (2-4KB/wave, per-wave waitcnt). Reduce: waves 0-3 sum 16
//    partials. Elementwise/publish: tid<256, bit-identical to r10.

#define T_STEPS 1024
#define TQ 16        // t-chunks for gx gemm grid

typedef unsigned short u16;
typedef unsigned long long u64;
typedef __attribute__((ext_vector_type(8))) __bf16 bf16x8;      // 8 bf16 = 4 VGPR
typedef __attribute__((ext_vector_type(4))) float float4v;      // MFMA C/D + f32 loads
typedef __attribute__((ext_vector_type(4))) unsigned short ushort4v;
typedef __attribute__((ext_vector_type(8))) unsigned short ushort8;

__device__ __forceinline__ float bf2f(u16 h) {
    unsigned u = ((unsigned)h) << 16;
    return __builtin_bit_cast(float, u);
}
__device__ __forceinline__ u16 f2bf(float f) {
    unsigned u = __builtin_bit_cast(unsigned, f);
    u += 0x7fff + ((u >> 16) & 1);   // RNE
    return (u16)(u >> 16);
}

__device__ __forceinline__ float4v mfma16(bf16x8 a, bf16x8 b, float4v c) {
    return __builtin_amdgcn_mfma_f32_16x16x32_bf16(a, b, c, 0, 0, 0);
}
__device__ __forceinline__ unsigned aload(const unsigned* p) {
    return __hip_atomic_load(p, __ATOMIC_RELAXED, __HIP_MEMORY_SCOPE_AGENT);
}
__device__ __forceinline__ void astore(unsigned* p, unsigned v) {
    __hip_atomic_store(p, v, __ATOMIC_RELAXED, __HIP_MEMORY_SCOPE_AGENT);
}
// opaque pin: value can no longer be rematerialized from its defining load
__device__ __forceinline__ void pin(bf16x8& v) {
    asm volatile("" : "+v"(v));
}
// cached 16B global->LDS (for producer-dispatch-ordered data: xpack in gx_gemm)
__device__ __forceinline__ void gld_lds16c(const void* g, void* l) {
    __builtin_amdgcn_global_load_lds(
        (const __attribute__((address_space(1))) unsigned*)g,
        (__attribute__((address_space(3))) unsigned*)l, 16, 0, 0);
}
// LLC-coherent 16B global->LDS (sc0|sc1 = 17): bypasses non-coherent L1/L2.
__device__ __forceinline__ void gld_lds16b(const void* g, void* l) {
    __builtin_amdgcn_global_load_lds(
        (const __attribute__((address_space(1))) unsigned*)g,
        (__attribute__((address_space(3))) unsigned*)l, 16, 0, 17);
}

// ---------------------------------------------------------------- init
__global__ void init_zero(unsigned* __restrict__ flags0,  // 1025*64
                          unsigned* __restrict__ flags1,  // 4*64 ring
                          unsigned* __restrict__ h0,      // 8192 (hist0 slot 0)
                          unsigned* __restrict__ h1) {    // 8192 (hist1 slot 0)
    int i = blockIdx.x * 256 + threadIdx.x;
    const int N0 = 65600, N1 = 256, N2 = 8192, N3 = 8192;
    for (int k = i; k < N0 + N1 + N2 + N3; k += 64 * 256) {
        if (k < N0) flags0[k] = 0u;
        else if (k < N0 + N1) flags1[k - N0] = 0u;
        else if (k < N0 + N1 + N2) h0[k - N0 - N1] = 0u;
        else h1[k - N0 - N1 - N2] = 0u;
    }
}

// ---------------------------------------------------------------- pack
// f32 -> bf16 A/B-frag tiles. dst[tile][kc][lane][8] =
//   src[rowbase+lane%16][kc*32+(lane/16)*8+j]
__device__ __forceinline__ void pack_one(const float* src, u16* dst, int tile, int rowbase) {
    int tid = threadIdx.x;
    ushort8* d = (ushort8*)dst;
#pragma unroll
    for (int it = 0; it < 8; ++it) {
        int c = tid + it * 256;
        int kc = c >> 6, lane = c & 63;
        const float4v* s4 = (const float4v*)(src + (((long)(rowbase + (lane & 15))) << 10)
                                                 + (kc << 5) + ((lane >> 4) << 3));
        float4v lo = s4[0], hi = s4[1];
        ushort8 o;
        o[0] = f2bf(lo[0]); o[1] = f2bf(lo[1]); o[2] = f2bf(lo[2]); o[3] = f2bf(lo[3]);
        o[4] = f2bf(hi[0]); o[5] = f2bf(hi[1]); o[6] = f2bf(hi[2]); o[7] = f2bf(hi[3]);
        d[tile * 2048 + c] = o;
    }
}

__global__ void pack_x(const float* __restrict__ src, u16* __restrict__ dst) {
    pack_one(src, dst, blockIdx.x, blockIdx.x << 4);   // rowbase = t*16
}

// 4 weight matrices in one dispatch: grid 1024, which = blockIdx>>8
__global__ void pack_w(const float* __restrict__ w0, const float* __restrict__ w1,
                       const float* __restrict__ w2, const float* __restrict__ w3,
                       u16* __restrict__ d0, u16* __restrict__ d1,
                       u16* __restrict__ d2, u16* __restrict__ d3) {
    int which = blockIdx.x >> 8, tile = blockIdx.x & 255;
    const float* s = (which == 0) ? w0 : (which == 1) ? w1 : (which == 2) ? w2 : w3;
    u16* d = (which == 0) ? d0 : (which == 1) ? d1 : (which == 2) ? d2 : d3;
    int rowbase = ((tile & 3) << 10) + ((tile >> 2) << 4);
    pack_one(s, d, tile, rowbase);
}

// ---------------------------------------------------------------- gx gemm (layer 0)
// K-split: wave w computes K-slice [256w,256w+256) for all 4 gates, reading only
// its own staged LDS quarter; reduce phase (wave w = gate w) sums partials.
__global__ __launch_bounds__(256, 1) void gx_gemm(
        const u16* __restrict__ xp, const bf16x8* __restrict__ wp,
        const float* __restrict__ bih, const float* __restrict__ bhh,
        u16* __restrict__ gx) {
    __shared__ u64 abuf[4096];              // 32 KB
    __shared__ float4v part[4][4][64];      // 16 KB  [kslice][gate][lane]
    int blk = blockIdx.x, tq = blockIdx.y;
    int tid = threadIdx.x, w = tid >> 6, L = tid & 63;
    int gc = (w << 10) + (blk << 4) + (L & 15);
    float bsum = bih[gc] + bhh[gc];

    bf16x8 wf[32];   // [gate][k] for this wave's K-slice
#pragma unroll
    for (int g = 0; g < 4; ++g) {
        const bf16x8* wpt = wp + (blk * 4 + g) * 2048 + (w * 8) * 64 + L;
#pragma unroll
        for (int k = 0; k < 8; ++k) wf[g * 8 + k] = wpt[k * 64];
    }
#pragma unroll
    for (int i = 0; i < 32; ++i) pin(wf[i]);
    const bf16x8* hp = (const bf16x8*)abuf;

    const int tch = T_STEPS / TQ;
    for (int tt = 0; tt < tch; ++tt) {
        int t = tq * tch + tt;
        const char* src = (const char*)xp + ((size_t)t << 15) + (w << 13) + (L << 4);
        char* dst = (char*)abuf + (w << 13);
#pragma unroll
        for (int i = 0; i < 8; ++i) gld_lds16c(src + i * 1024, dst + i * 1024);
        __builtin_amdgcn_s_waitcnt(0);          // own stage done (own quarter only)
        __builtin_amdgcn_sched_barrier(0);

        float4v acc[4];
#pragma unroll
        for (int g = 0; g < 4; ++g) acc[g] = float4v{0.f, 0.f, 0.f, 0.f};
#pragma unroll
        for (int k = 0; k < 8; ++k) {
            bf16x8 a = hp[(8 * w + k) * 64 + L];
#pragma unroll
            for (int g = 0; g < 4; ++g) acc[g] = mfma16(a, wf[g * 8 + k], acc[g]);
        }
#pragma unroll
        for (int g = 0; g < 4; ++g) part[w][g][L] = acc[g];
        __syncthreads();
        float4v s = part[0][w][L] + part[1][w][L] + part[2][w][L] + part[3][w][L];
        ushort4v o;
#pragma unroll
        for (int r = 0; r < 4; ++r) o[r] = f2bf(s[r] + bsum);
        ((ushort4v*)gx)[((t * 64 + blk) * 4 + w) * 64 + L] = o;
        __syncthreads();    // part reusable next iteration
    }
}

// ---------------------------------------------------------------- fused pipelined scan
// 1024 threads, 16 waves. Blocks 0..63: layer 0; 64..127: layer 1.
// L0: wave w owns kc [2w,2w+2) of K=1024 -> 8 weight frags (32 VGPR).
// L1: concat-K 2048 ([Wih1|Whh1]); wave w owns kc [4w,4w+4): w<8 -> Wih1,
//     w>=8 -> Whh1 -> 16 weight frags (64 VGPR, proven-resident footprint).
__global__ __launch_bounds__(1024, 1) void lstm_scan2(
        const u16* __restrict__ gx0,     // layer-0 gates_x (C-frag, both biases)
        const bf16x8* __restrict__ wpHh0,
        const bf16x8* __restrict__ wpIh1, const bf16x8* __restrict__ wpHh1,
        const float* __restrict__ bih1, const float* __restrict__ bhh1,
        unsigned* hist0w,                // 1025 slots x 8192 u32 (A-frag h0)
        unsigned* hist1x,                // 1024 slots (slots 1..1024, = dead xpack)
        unsigned* h1s0,                  // slot 0 of hist1 (zeroed)
        unsigned* flags0,                // [1025][64] 0/1
        unsigned* flags1,                // [4][64] ring, tag = step
        float* outbase) {                // d_out
    __shared__ u64 hbuf[8192];               // 64 KB
    __shared__ float4v lds_part[16][4][64];  // 64 KB [kslice][gate][lane]
    __shared__ float4v lds_g[4][64];         // 4 KB

    int tid = threadIdx.x, w = tid >> 6, L = tid & 63;
    int m = tid >> 4, j = tid & 15;            // roles valid for tid<256
    int Lc = ((m >> 2) << 4) | j, rr = m & 3;
    int layer = (blockIdx.x >= 64);
    int blk = blockIdx.x & 63;
    int hcol = (blk << 4) + j;
    int kcw = hcol >> 5, laneg = (hcol >> 3) & 3, jj = hcol & 7;
    int hwoff32 = ((kcw * 64 + m + (laneg << 4)) << 2) + (jj >> 1);
    float* fH = outbase + 16777216 + (layer ? 16384 : 0);
    float* fC = outbase + 16777216 + 32768 + (layer ? 16384 : 0);
    float c = 0.f;
    const bf16x8* hp = (const bf16x8*)hbuf;

    if (!layer) {
        // ---------------- layer 0: K=1024, wave w owns kc [2w,2w+2) ----------------
        bf16x8 wf[8];   // [gate][k], 32 VGPR — resident
#pragma unroll
        for (int g = 0; g < 4; ++g) {
            const bf16x8* wsrc = wpHh0 + (blk * 4 + g) * 2048 + (2 * w) * 64 + L;
#pragma unroll
            for (int k = 0; k < 2; ++k) wf[g * 2 + k] = wsrc[k * 64];
        }
#pragma unroll
        for (int i = 0; i < 8; ++i) pin(wf[i]);

        for (int t = 0; t < T_STEPS; ++t) {
            ushort4v gxv = {0, 0, 0, 0};
            if (w < 4) gxv = ((const ushort4v*)gx0)[((t * 64 + blk) * 4 + w) * 64 + L];
            if (t > 0) {   // every wave polls all 64 flags (lane L <-> flag L)
                unsigned v;
                do { v = aload(&flags0[t * 64 + L]); }
                while (__ballot(v != 0u) != ~0ull);
            }
            {   // stage own 2KB slice of h0(t) -> LDS
                const char* src = (const char*)hist0w + ((size_t)t << 15) + (w << 11) + (L << 4);
                char* dst = (char*)hbuf + (w << 11);
#pragma unroll
                for (int i = 0; i < 2; ++i) gld_lds16b(src + i * 1024, dst + i * 1024);
            }
            __builtin_amdgcn_s_waitcnt(0);
            __builtin_amdgcn_sched_barrier(0);

            float4v acc[4];
#pragma unroll
            for (int g = 0; g < 4; ++g) acc[g] = float4v{0.f, 0.f, 0.f, 0.f};
#pragma unroll
            for (int k = 0; k < 2; ++k) {
                bf16x8 a = hp[(2 * w + k) * 64 + L];
#pragma unroll
                for (int g = 0; g < 4; ++g) acc[g] = mfma16(a, wf[g * 2 + k], acc[g]);
            }
#pragma unroll
            for (int g = 0; g < 4; ++g) lds_part[w][g][L] = acc[g];
            __syncthreads();

            if (w < 4) {   // reduce: wave w = gate w
                float4v s = lds_part[0][w][L];
#pragma unroll
                for (int ks = 1; ks < 16; ++ks) s = s + lds_part[ks][w][L];
                float4v g4;
#pragma unroll
                for (int r = 0; r < 4; ++r) g4[r] = s[r] + bf2f(gxv[r]);
                lds_g[w][L] = g4;
            }
            __syncthreads();

            if (tid < 256) {
                float gi = lds_g[0][Lc][rr], gf = lds_g[1][Lc][rr];
                float gg = lds_g[2][Lc][rr], go = lds_g[3][Lc][rr];
                float iv = 1.f / (1.f + __expf(-gi));
                float fv = 1.f / (1.f + __expf(-gf));
                float gv = 1.f - 2.f / (1.f + __expf(2.f * gg));
                float ov = 1.f / (1.f + __expf(-go));
                c = fv * c + iv * gv;
                float h = ov * (1.f - 2.f / (1.f + __expf(2.f * c)));
                unsigned hb = f2bf(h);
                unsigned other = (unsigned)__shfl_xor((int)hb, 1);
                if (!(tid & 1))
                    astore(hist0w + ((size_t)(t + 1) << 13) + hwoff32, hb | (other << 16));
                if (t == T_STEPS - 1) {
                    fH[(m << 10) + hcol] = h;
                    fC[(m << 10) + hcol] = c;
                }
            }
            __builtin_amdgcn_s_waitcnt(0);
            __syncthreads();
            if (tid == 0) astore(&flags0[(t + 1) * 64 + blk], 1u);
        }
    } else {
        // ---------------- layer 1: concat K=2048, wave w owns kc [4w,4w+4) --------
        bf16x8 wf[16];   // [gate][k], 64 VGPR — resident (r11-proven footprint)
        const bf16x8* wbase = (w < 8) ? wpIh1 : wpHh1;
        int kcb = (w < 8) ? (4 * w) : (4 * (w - 8));
#pragma unroll
        for (int g = 0; g < 4; ++g) {
            const bf16x8* wsrc = wbase + (blk * 4 + g) * 2048 + kcb * 64 + L;
#pragma unroll
            for (int k = 0; k < 4; ++k) wf[g * 4 + k] = wsrc[k * 64];
        }
#pragma unroll
        for (int i = 0; i < 16; ++i) pin(wf[i]);
        int gc = (w << 10) + (blk << 4) + (L & 15);
        float bsum = (w < 4) ? (bih1[gc] + bhh1[gc]) : 0.f;

        for (int t = 0; t < T_STEPS; ++t) {
            if (w < 8) {   // A-half waves need out0(t) = hist0 slot t+1
                unsigned v;
                do { v = aload(&flags0[(t + 1) * 64 + L]); }
                while (__ballot(v != 0u) != ~0ull);
            } else if (t > 0) {   // B-half waves need h1(t)
                unsigned v;
                do { v = aload(&flags1[(t & 3) * 64 + L]); }
                while (__ballot(v == (unsigned)t) != ~0ull);
            }
            {   // stage own 4KB slice -> LDS (dst = hbuf + w*4KB)
                const char* src = (w < 8)
                    ? ((const char*)hist0w + ((size_t)(t + 1) << 15) + (w << 12) + (L << 4))
                    : ((t == 0)
                        ? ((const char*)h1s0 + ((w - 8) << 12) + (L << 4))
                        : ((const char*)hist1x + ((size_t)(t - 1) << 15) + ((w - 8) << 12) + (L << 4)));
                char* dst = (char*)hbuf + (w << 12);
#pragma unroll
                for (int i = 0; i < 4; ++i) gld_lds16b(src + i * 1024, dst + i * 1024);
            }
            __builtin_amdgcn_s_waitcnt(0);
            __builtin_amdgcn_sched_barrier(0);

            float4v acc[4];
#pragma unroll
            for (int g = 0; g < 4; ++g) acc[g] = float4v{0.f, 0.f, 0.f, 0.f};
#pragma unroll
            for (int k = 0; k < 4; ++k) {
                bf16x8 a = hp[(4 * w + k) * 64 + L];
#pragma unroll
                for (int g = 0; g < 4; ++g) acc[g] = mfma16(a, wf[g * 4 + k], acc[g]);
            }
#pragma unroll
            for (int g = 0; g < 4; ++g) lds_part[w][g][L] = acc[g];
            __syncthreads();

            if (w < 4) {   // reduce: wave w = gate w
                float4v s = lds_part[0][w][L];
#pragma unroll
                for (int ks = 1; ks < 16; ++ks) s = s + lds_part[ks][w][L];
                float4v g4;
#pragma unroll
                for (int r = 0; r < 4; ++r) g4[r] = s[r] + bsum;
                lds_g[w][L] = g4;
            }
            __syncthreads();

            float h = 0.f;
            if (tid < 256) {
                float gi = lds_g[0][Lc][rr], gf = lds_g[1][Lc][rr];
                float gg = lds_g[2][Lc][rr], go = lds_g[3][Lc][rr];
                float iv = 1.f / (1.f + __expf(-gi));
                float fv = 1.f / (1.f + __expf(-gf));
                float gv = 1.f - 2.f / (1.f + __expf(2.f * gg));
                float ov = 1.f / (1.f + __expf(-go));
                c = fv * c + iv * gv;
                h = ov * (1.f - 2.f / (1.f + __expf(2.f * c)));
                unsigned hb = f2bf(h);
                unsigned other = (unsigned)__shfl_xor((int)hb, 1);
                if (!(tid & 1))   // slot t+1 lives at hist1x + t*32KB
                    astore(hist1x + ((size_t)t << 13) + hwoff32, hb | (other << 16));
            }
            __builtin_amdgcn_s_waitcnt(0);
            __syncthreads();
            if (tid == 0) astore(&flags1[(((t + 1) & 3) << 6) + blk], (unsigned)(t + 1));
            // not ring-consumed: store after the flag, drains under next poll
            if (tid < 256) {
                outbase[(t << 14) + (m << 10) + hcol] = h;
                if (t == T_STEPS - 1) {
                    fH[(m << 10) + hcol] = h;
                    fC[(m << 10) + hcol] = c;
                }
            }
        }
    }
}

// ---------------------------------------------------------------- launch
extern "C" void kernel_launch(void* const* d_in, const int* in_sizes, int n_in,
                              void* d_out, int out_size, void* d_ws, size_t ws_size,
                              hipStream_t stream) {
    const float* x    = (const float*)d_in[0];
    const float* Wih0 = (const float*)d_in[1];
    const float* bih0 = (const float*)d_in[2];
    const float* Whh0 = (const float*)d_in[3];
    const float* bhh0 = (const float*)d_in[4];
    const float* Wih1 = (const float*)d_in[5];
    const float* bih1 = (const float*)d_in[6];
    const float* Whh1 = (const float*)d_in[7];
    const float* bhh1 = (const float*)d_in[8];
    float* out = (float*)d_out;

    char* ws = (char*)d_ws;
    u16* wpIh0 = (u16*)(ws + 0);            //  8,388,608
    u16* wpHh0 = (u16*)(ws + 8388608);      //  8,388,608
    u16* wpIh1 = (u16*)(ws + 16777216);     //  8,388,608
    u16* wpHh1 = (u16*)(ws + 25165824);     //  8,388,608
    u16* xpack = (u16*)(ws + 33554432);     // 33,554,432 (reused as hist1 slots 1..1024)
    u16* hist0 = (u16*)(ws + 67108864);     // 33,587,200 (1025 x 32KB)
    u16* h1s0  = (u16*)(ws + 100696064);    //     32,768 (hist1 slot 0)
    u16* gxbuf = (u16*)(ws + 100728832);    // 134,217,728
    unsigned* flags0 = (unsigned*)(ws + 234946560); // 262,400
    unsigned* flags1 = (unsigned*)(ws + 235208960); //   1,024 -> 235,209,984 total

    init_zero<<<dim3(64), dim3(256), 0, stream>>>(flags0, flags1,
                                                  (unsigned*)hist0, (unsigned*)h1s0);
    pack_w<<<dim3(1024), dim3(256), 0, stream>>>(Wih0, Whh0, Wih1, Whh1,
                                                 wpIh0, wpHh0, wpIh1, wpHh1);
    pack_x<<<dim3(1024), dim3(256), 0, stream>>>(x, xpack);
    gx_gemm<<<dim3(64, TQ), dim3(256), 0, stream>>>(
        xpack, (const bf16x8*)wpIh0, bih0, bhh0, gxbuf);
    lstm_scan2<<<dim3(128), dim3(1024), 0, stream>>>(
        gxbuf, (const bf16x8*)wpHh0, (const bf16x8*)wpIh1, (const bf16x8*)wpHh1,
        bih1, bhh1, (unsigned*)hist0, (unsigned*)xpack, (unsigned*)h1s0,
        flags0, flags1, out);
}

// Round 8
// 4808.567 us; speedup vs baseline: 1.1886x; 1.0327x over previous
//
#include <hip/hip_runtime.h>

// LSTM T=1024 B=16 I=H=1024 L=2. f32 in/out, bf16 MFMA internally.
// Round 13: r10 structure (8 waves, 64+64 blocks, best measured) +
//  (a) amdgpu_waves_per_eu(2,2): RA budget 256 VGPR -> L1's 32-frag weight
//      set (128 VGPR) truly resident (r9/r10 heuristic chose 104 and spilled).
//  (b) direct global->VGPR A-frag loads (sc0|sc1, 16B) replacing the
//      global->LDS->VGPR staging hop: since the K-split each wave reads only
//      its own slice, and hist layout IS A-frag layout. hbuf deleted
//      (scan LDS 100KB -> 36KB). Same s_waitcnt(0)+sched_barrier(0) fence.
//  Ring/flags/publish/reduce/elementwise identical to r10 (proven).

#define T_STEPS 1024
#define TQ 16        // t-chunks for gx gemm grid

typedef unsigned short u16;
typedef unsigned long long u64;
typedef __attribute__((ext_vector_type(8))) __bf16 bf16x8;      // 8 bf16 = 4 VGPR
typedef __attribute__((ext_vector_type(4))) float float4v;      // MFMA C/D + f32 loads
typedef __attribute__((ext_vector_type(4))) unsigned short ushort4v;
typedef __attribute__((ext_vector_type(8))) unsigned short ushort8;

__device__ __forceinline__ float bf2f(u16 h) {
    unsigned u = ((unsigned)h) << 16;
    return __builtin_bit_cast(float, u);
}
__device__ __forceinline__ u16 f2bf(float f) {
    unsigned u = __builtin_bit_cast(unsigned, f);
    u += 0x7fff + ((u >> 16) & 1);   // RNE
    return (u16)(u >> 16);
}

__device__ __forceinline__ float4v mfma16(bf16x8 a, bf16x8 b, float4v c) {
    return __builtin_amdgcn_mfma_f32_16x16x32_bf16(a, b, c, 0, 0, 0);
}
__device__ __forceinline__ unsigned aload(const unsigned* p) {
    return __hip_atomic_load(p, __ATOMIC_RELAXED, __HIP_MEMORY_SCOPE_AGENT);
}
__device__ __forceinline__ void astore(unsigned* p, unsigned v) {
    __hip_atomic_store(p, v, __ATOMIC_RELAXED, __HIP_MEMORY_SCOPE_AGENT);
}
// opaque pin: value can no longer be rematerialized from its defining load
__device__ __forceinline__ void pin(bf16x8& v) {
    asm volatile("" : "+v"(v));
}
// LLC-coherent 16B global->VGPR load (sc0 sc1): bypasses non-coherent L1/L2.
// Completion NOT tracked by compiler: caller must fence with
// s_waitcnt(0) + sched_barrier(0) before consuming (rule-#18 pattern).
__device__ __forceinline__ bf16x8 gload16b(const void* p) {
    bf16x8 r;
    asm volatile("global_load_dwordx4 %0, %1, off sc0 sc1"
                 : "=v"(r) : "v"(p) : "memory");
    return r;
}
// cached 16B global->LDS (for producer-dispatch-ordered data: xpack in gx_gemm)
__device__ __forceinline__ void gld_lds16c(const void* g, void* l) {
    __builtin_amdgcn_global_load_lds(
        (const __attribute__((address_space(1))) unsigned*)g,
        (__attribute__((address_space(3))) unsigned*)l, 16, 0, 0);
}

// ---------------------------------------------------------------- init
__global__ void init_zero(unsigned* __restrict__ flags0,  // 1025*64
                          unsigned* __restrict__ flags1,  // 4*64 ring
                          unsigned* __restrict__ h0,      // 8192 (hist0 slot 0)
                          unsigned* __restrict__ h1) {    // 8192 (hist1 slot 0)
    int i = blockIdx.x * 256 + threadIdx.x;
    const int N0 = 65600, N1 = 256, N2 = 8192, N3 = 8192;
    for (int k = i; k < N0 + N1 + N2 + N3; k += 64 * 256) {
        if (k < N0) flags0[k] = 0u;
        else if (k < N0 + N1) flags1[k - N0] = 0u;
        else if (k < N0 + N1 + N2) h0[k - N0 - N1] = 0u;
        else h1[k - N0 - N1 - N2] = 0u;
    }
}

// ---------------------------------------------------------------- pack
// f32 -> bf16 A/B-frag tiles. dst[tile][kc][lane][8] =
//   src[rowbase+lane%16][kc*32+(lane/16)*8+j]
__device__ __forceinline__ void pack_one(const float* src, u16* dst, int tile, int rowbase) {
    int tid = threadIdx.x;
    ushort8* d = (ushort8*)dst;
#pragma unroll
    for (int it = 0; it < 8; ++it) {
        int c = tid + it * 256;
        int kc = c >> 6, lane = c & 63;
        const float4v* s4 = (const float4v*)(src + (((long)(rowbase + (lane & 15))) << 10)
                                                 + (kc << 5) + ((lane >> 4) << 3));
        float4v lo = s4[0], hi = s4[1];
        ushort8 o;
        o[0] = f2bf(lo[0]); o[1] = f2bf(lo[1]); o[2] = f2bf(lo[2]); o[3] = f2bf(lo[3]);
        o[4] = f2bf(hi[0]); o[5] = f2bf(hi[1]); o[6] = f2bf(hi[2]); o[7] = f2bf(hi[3]);
        d[tile * 2048 + c] = o;
    }
}

__global__ void pack_x(const float* __restrict__ src, u16* __restrict__ dst) {
    pack_one(src, dst, blockIdx.x, blockIdx.x << 4);   // rowbase = t*16
}

// 4 weight matrices in one dispatch: grid 1024, which = blockIdx>>8
__global__ void pack_w(const float* __restrict__ w0, const float* __restrict__ w1,
                       const float* __restrict__ w2, const float* __restrict__ w3,
                       u16* __restrict__ d0, u16* __restrict__ d1,
                       u16* __restrict__ d2, u16* __restrict__ d3) {
    int which = blockIdx.x >> 8, tile = blockIdx.x & 255;
    const float* s = (which == 0) ? w0 : (which == 1) ? w1 : (which == 2) ? w2 : w3;
    u16* d = (which == 0) ? d0 : (which == 1) ? d1 : (which == 2) ? d2 : d3;
    int rowbase = ((tile & 3) << 10) + ((tile >> 2) << 4);
    pack_one(s, d, tile, rowbase);
}

// ---------------------------------------------------------------- gx gemm (layer 0)
// K-split: wave w computes K-slice [256w,256w+256) for all 4 gates, reading only
// its own staged LDS quarter; reduce phase (wave w = gate w) sums partials.
__global__ __launch_bounds__(256, 1) void gx_gemm(
        const u16* __restrict__ xp, const bf16x8* __restrict__ wp,
        const float* __restrict__ bih, const float* __restrict__ bhh,
        u16* __restrict__ gx) {
    __shared__ u64 abuf[4096];              // 32 KB
    __shared__ float4v part[4][4][64];      // 16 KB  [kslice][gate][lane]
    int blk = blockIdx.x, tq = blockIdx.y;
    int tid = threadIdx.x, w = tid >> 6, L = tid & 63;
    int gc = (w << 10) + (blk << 4) + (L & 15);
    float bsum = bih[gc] + bhh[gc];

    bf16x8 wf[32];   // [gate][k] for this wave's K-slice
#pragma unroll
    for (int g = 0; g < 4; ++g) {
        const bf16x8* wpt = wp + (blk * 4 + g) * 2048 + (w * 8) * 64 + L;
#pragma unroll
        for (int k = 0; k < 8; ++k) wf[g * 8 + k] = wpt[k * 64];
    }
#pragma unroll
    for (int i = 0; i < 32; ++i) pin(wf[i]);
    const bf16x8* hp = (const bf16x8*)abuf;

    const int tch = T_STEPS / TQ;
    for (int tt = 0; tt < tch; ++tt) {
        int t = tq * tch + tt;
        const char* src = (const char*)xp + ((size_t)t << 15) + (w << 13) + (L << 4);
        char* dst = (char*)abuf + (w << 13);
#pragma unroll
        for (int i = 0; i < 8; ++i) gld_lds16c(src + i * 1024, dst + i * 1024);
        __builtin_amdgcn_s_waitcnt(0);          // own stage done (own quarter only)
        __builtin_amdgcn_sched_barrier(0);

        float4v acc[4];
#pragma unroll
        for (int g = 0; g < 4; ++g) acc[g] = float4v{0.f, 0.f, 0.f, 0.f};
#pragma unroll
        for (int k = 0; k < 8; ++k) {
            bf16x8 a = hp[(8 * w + k) * 64 + L];
#pragma unroll
            for (int g = 0; g < 4; ++g) acc[g] = mfma16(a, wf[g * 8 + k], acc[g]);
        }
#pragma unroll
        for (int g = 0; g < 4; ++g) part[w][g][L] = acc[g];
        __syncthreads();
        float4v s = part[0][w][L] + part[1][w][L] + part[2][w][L] + part[3][w][L];
        ushort4v o;
#pragma unroll
        for (int r = 0; r < 4; ++r) o[r] = f2bf(s[r] + bsum);
        ((ushort4v*)gx)[((t * 64 + blk) * 4 + w) * 64 + L] = o;
        __syncthreads();    // part reusable next iteration
    }
}

// ---------------------------------------------------------------- fused pipelined scan
// 512 threads, 8 waves, 2 waves/SIMD -> 256-VGPR budget (amdgpu_waves_per_eu).
// L0: wave w owns kc [4w,4w+4) of K=1024 (16 weight frags resident).
// L1: concat-K 2048 ([Wih1|Whh1]); wave w<4 -> Wih1 kc[8w..8w+8),
//     w>=4 -> Whh1 kc[8(w-4)..) (32 weight frags, resident at 256 budget).
// A-operands loaded DIRECTLY global->VGPR (hist layout == A-frag layout).
__global__ __launch_bounds__(512)
__attribute__((amdgpu_waves_per_eu(2, 2)))
void lstm_scan2(
        const u16* __restrict__ gx0,     // layer-0 gates_x (C-frag, both biases)
        const bf16x8* __restrict__ wpHh0,
        const bf16x8* __restrict__ wpIh1, const bf16x8* __restrict__ wpHh1,
        const float* __restrict__ bih1, const float* __restrict__ bhh1,
        unsigned* hist0w,                // 1025 slots x 8192 u32 (A-frag h0)
        unsigned* hist1x,                // 1024 slots (slots 1..1024, = dead xpack)
        unsigned* h1s0,                  // slot 0 of hist1 (zeroed)
        unsigned* flags0,                // [1025][64] 0/1
        unsigned* flags1,                // [4][64] ring, tag = step
        float* outbase) {                // d_out
    __shared__ float4v lds_part[8][4][64];  // 32 KB [kslice][gate][lane]
    __shared__ float4v lds_g[4][64];        // 4 KB

    int tid = threadIdx.x, w = tid >> 6, L = tid & 63;
    int m = tid >> 4, j = tid & 15;            // roles valid for tid<256
    int Lc = ((m >> 2) << 4) | j, rr = m & 3;
    int layer = (blockIdx.x >= 64);
    int blk = blockIdx.x & 63;
    int hcol = (blk << 4) + j;
    int kcw = hcol >> 5, laneg = (hcol >> 3) & 3, jj = hcol & 7;
    int hwoff32 = ((kcw * 64 + m + (laneg << 4)) << 2) + (jj >> 1);
    float* fH = outbase + 16777216 + (layer ? 16384 : 0);
    float* fC = outbase + 16777216 + 32768 + (layer ? 16384 : 0);
    float c = 0.f;

    if (!layer) {
        // ---------------- layer 0: K=1024, wave w owns kc [4w,4w+4) ----------------
        bf16x8 wf[16];   // [gate][k], 64 VGPR — resident
#pragma unroll
        for (int g = 0; g < 4; ++g) {
            const bf16x8* wsrc = wpHh0 + (blk * 4 + g) * 2048 + (4 * w) * 64 + L;
#pragma unroll
            for (int k = 0; k < 4; ++k) wf[g * 4 + k] = wsrc[k * 64];
        }
#pragma unroll
        for (int i = 0; i < 16; ++i) pin(wf[i]);

        for (int t = 0; t < T_STEPS; ++t) {
            ushort4v gxv = {0, 0, 0, 0};
            if (w < 4) gxv = ((const ushort4v*)gx0)[((t * 64 + blk) * 4 + w) * 64 + L];
            if (t > 0) {   // every wave polls all 64 flags (lane L <-> flag L)
                unsigned v;
                do { v = aload(&flags0[t * 64 + L]); }
                while (__ballot(v != 0u) != ~0ull);
            }
            // direct A-frag loads: own 4KB slice of h0(t)
            const char* base = (const char*)hist0w + ((size_t)t << 15) + (w << 12) + (L << 4);
            bf16x8 a0 = gload16b(base);
            bf16x8 a1 = gload16b(base + 1024);
            bf16x8 a2 = gload16b(base + 2048);
            bf16x8 a3 = gload16b(base + 3072);
            __builtin_amdgcn_s_waitcnt(0);
            __builtin_amdgcn_sched_barrier(0);

            float4v acc[4];
#pragma unroll
            for (int g = 0; g < 4; ++g) acc[g] = float4v{0.f, 0.f, 0.f, 0.f};
#pragma unroll
            for (int g = 0; g < 4; ++g) acc[g] = mfma16(a0, wf[g * 4 + 0], acc[g]);
#pragma unroll
            for (int g = 0; g < 4; ++g) acc[g] = mfma16(a1, wf[g * 4 + 1], acc[g]);
#pragma unroll
            for (int g = 0; g < 4; ++g) acc[g] = mfma16(a2, wf[g * 4 + 2], acc[g]);
#pragma unroll
            for (int g = 0; g < 4; ++g) acc[g] = mfma16(a3, wf[g * 4 + 3], acc[g]);
#pragma unroll
            for (int g = 0; g < 4; ++g) lds_part[w][g][L] = acc[g];
            __syncthreads();

            if (w < 4) {   // reduce: wave w = gate w
                float4v s = lds_part[0][w][L] + lds_part[1][w][L]
                          + lds_part[2][w][L] + lds_part[3][w][L]
                          + lds_part[4][w][L] + lds_part[5][w][L]
                          + lds_part[6][w][L] + lds_part[7][w][L];
                float4v g4;
#pragma unroll
                for (int r = 0; r < 4; ++r) g4[r] = s[r] + bf2f(gxv[r]);
                lds_g[w][L] = g4;
            }
            __syncthreads();

            if (tid < 256) {
                float gi = lds_g[0][Lc][rr], gf = lds_g[1][Lc][rr];
                float gg = lds_g[2][Lc][rr], go = lds_g[3][Lc][rr];
                float iv = 1.f / (1.f + __expf(-gi));
                float fv = 1.f / (1.f + __expf(-gf));
                float gv = 1.f - 2.f / (1.f + __expf(2.f * gg));
                float ov = 1.f / (1.f + __expf(-go));
                c = fv * c + iv * gv;
                float h = ov * (1.f - 2.f / (1.f + __expf(2.f * c)));
                unsigned hb = f2bf(h);
                unsigned other = (unsigned)__shfl_xor((int)hb, 1);
                if (!(tid & 1))
                    astore(hist0w + ((size_t)(t + 1) << 13) + hwoff32, hb | (other << 16));
                if (t == T_STEPS - 1) {
                    fH[(m << 10) + hcol] = h;
                    fC[(m << 10) + hcol] = c;
                }
            }
            __builtin_amdgcn_s_waitcnt(0);
            __syncthreads();
            if (tid == 0) astore(&flags0[(t + 1) * 64 + blk], 1u);
        }
    } else {
        // ---------------- layer 1: concat K=2048, wave w owns 8 kc ----------------
        bf16x8 wf[32];   // [gate][k], 128 VGPR — resident at 256 budget
#pragma unroll
        for (int g = 0; g < 4; ++g) {
            const bf16x8* wsrc = (w < 4)
                ? (wpIh1 + (blk * 4 + g) * 2048 + (8 * w) * 64 + L)
                : (wpHh1 + (blk * 4 + g) * 2048 + (8 * (w - 4)) * 64 + L);
#pragma unroll
            for (int k = 0; k < 8; ++k) wf[g * 8 + k] = wsrc[k * 64];
        }
#pragma unroll
        for (int i = 0; i < 32; ++i) pin(wf[i]);
        int gc = (w << 10) + (blk << 4) + (L & 15);
        float bsum = (w < 4) ? (bih1[gc] + bhh1[gc]) : 0.f;

        for (int t = 0; t < T_STEPS; ++t) {
            if (w < 4) {   // A-half waves need out0(t) = hist0 slot t+1
                unsigned v;
                do { v = aload(&flags0[(t + 1) * 64 + L]); }
                while (__ballot(v != 0u) != ~0ull);
            } else if (t > 0) {   // B-half waves need h1(t)
                unsigned v;
                do { v = aload(&flags1[(t & 3) * 64 + L]); }
                while (__ballot(v == (unsigned)t) != ~0ull);
            }
            // direct A-frag loads: own 8KB slice (A-half: out0(t); B-half: h1(t))
            const char* base = (w < 4)
                ? ((const char*)hist0w + ((size_t)(t + 1) << 15) + (w << 13) + (L << 4))
                : ((t == 0)
                    ? ((const char*)h1s0 + ((w - 4) << 13) + (L << 4))
                    : ((const char*)hist1x + ((size_t)(t - 1) << 15) + ((w - 4) << 13) + (L << 4)));
            bf16x8 a[8];
#pragma unroll
            for (int k = 0; k < 8; ++k) a[k] = gload16b(base + k * 1024);
            __builtin_amdgcn_s_waitcnt(0);
            __builtin_amdgcn_sched_barrier(0);

            float4v acc[4];
#pragma unroll
            for (int g = 0; g < 4; ++g) acc[g] = float4v{0.f, 0.f, 0.f, 0.f};
#pragma unroll
            for (int k = 0; k < 8; ++k) {
#pragma unroll
                for (int g = 0; g < 4; ++g) acc[g] = mfma16(a[k], wf[g * 8 + k], acc[g]);
            }
#pragma unroll
            for (int g = 0; g < 4; ++g) lds_part[w][g][L] = acc[g];
            __syncthreads();

            if (w < 4) {   // reduce: wave w = gate w
                float4v s = lds_part[0][w][L] + lds_part[1][w][L]
                          + lds_part[2][w][L] + lds_part[3][w][L]
                          + lds_part[4][w][L] + lds_part[5][w][L]
                          + lds_part[6][w][L] + lds_part[7][w][L];
                float4v g4;
#pragma unroll
                for (int r = 0; r < 4; ++r) g4[r] = s[r] + bsum;
                lds_g[w][L] = g4;
            }
            __syncthreads();

            float h = 0.f;
            if (tid < 256) {
                float gi = lds_g[0][Lc][rr], gf = lds_g[1][Lc][rr];
                float gg = lds_g[2][Lc][rr], go = lds_g[3][Lc][rr];
                float iv = 1.f / (1.f + __expf(-gi));
                float fv = 1.f / (1.f + __expf(-gf));
                float gv = 1.f - 2.f / (1.f + __expf(2.f * gg));
                float ov = 1.f / (1.f + __expf(-go));
                c = fv * c + iv * gv;
                h = ov * (1.f - 2.f / (1.f + __expf(2.f * c)));
                unsigned hb = f2bf(h);
                unsigned other = (unsigned)__shfl_xor((int)hb, 1);
                if (!(tid & 1))   // slot t+1 lives at hist1x + t*32KB
                    astore(hist1x + ((size_t)t << 13) + hwoff32, hb | (other << 16));
            }
            __builtin_amdgcn_s_waitcnt(0);
            __syncthreads();
            if (tid == 0) astore(&flags1[(((t + 1) & 3) << 6) + blk], (unsigned)(t + 1));
            // not ring-consumed: store after the flag, drains under next poll
            if (tid < 256) {
                outbase[(t << 14) + (m << 10) + hcol] = h;
                if (t == T_STEPS - 1) {
                    fH[(m << 10) + hcol] = h;
                    fC[(m << 10) + hcol] = c;
                }
            }
        }
    }
}

// ---------------------------------------------------------------- launch
extern "C" void kernel_launch(void* const* d_in, const int* in_sizes, int n_in,
                              void* d_out, int out_size, void* d_ws, size_t ws_size,
                              hipStream_t stream) {
    const float* x    = (const float*)d_in[0];
    const float* Wih0 = (const float*)d_in[1];
    const float* bih0 = (const float*)d_in[2];
    const float* Whh0 = (const float*)d_in[3];
    const float* bhh0 = (const float*)d_in[4];
    const float* Wih1 = (const float*)d_in[5];
    const float* bih1 = (const float*)d_in[6];
    const float* Whh1 = (const float*)d_in[7];
    const float* bhh1 = (const float*)d_in[8];
    float* out = (float*)d_out;

    char* ws = (char*)d_ws;
    u16* wpIh0 = (u16*)(ws + 0);            //  8,388,608
    u16* wpHh0 = (u16*)(ws + 8388608);      //  8,388,608
    u16* wpIh1 = (u16*)(ws + 16777216);     //  8,388,608
    u16* wpHh1 = (u16*)(ws + 25165824);     //  8,388,608
    u16* xpack = (u16*)(ws + 33554432);     // 33,554,432 (reused as hist1 slots 1..1024)
    u16* hist0 = (u16*)(ws + 67108864);     // 33,587,200 (1025 x 32KB)
    u16* h1s0  = (u16*)(ws + 100696064);    //     32,768 (hist1 slot 0)
    u16* gxbuf = (u16*)(ws + 100728832);    // 134,217,728
    unsigned* flags0 = (unsigned*)(ws + 234946560); // 262,400
    unsigned* flags1 = (unsigned*)(ws + 235208960); //   1,024 -> 235,209,984 total

    init_zero<<<dim3(64), dim3(256), 0, stream>>>(flags0, flags1,
                                                  (unsigned*)hist0, (unsigned*)h1s0);
    pack_w<<<dim3(1024), dim3(256), 0, stream>>>(Wih0, Whh0, Wih1, Whh1,
                                                 wpIh0, wpHh0, wpIh1, wpHh1);
    pack_x<<<dim3(1024), dim3(256), 0, stream>>>(x, xpack);
    gx_gemm<<<dim3(64, TQ), dim3(256), 0, stream>>>(
        xpack, (const bf16x8*)wpIh0, bih0, bhh0, gxbuf);
    lstm_scan2<<<dim3(128), dim3(512), 0, stream>>>(
        gxbuf, (const bf16x8*)wpHh0, (const bf16x8*)wpIh1, (const bf16x8*)wpHh1,
        bih1, bhh1, (unsigned*)hist0, (unsigned*)xpack, (unsigned*)h1s0,
        flags0, flags1, out);
}